// Round 8
// baseline (630.842 us; speedup 1.0000x reference)
//
#include <hip/hip_runtime.h>

// Problem constants (fixed by the reference):
//   B=4, NV=100000, F=200000, D=64
#define BB    4
#define NVV   100000
#define FFC   200000
#define DD    64
#define TOTV  (BB * NVV)          // 400000 vertices
#define TOTF  (BB * FFC)          // 800000 faces
#define TOTE  (TOTF * 6)          // 4800000 adjacency entries
#define NREP  8                   // counter/cursor replicas (spread hot atomics)
#define NB_SCAN ((TOTV + 1023) / 1024)   // 391 scan blocks (256 thr x int4)

// ---------------------------------------------------------------------------
// CSR-build + gather path. Round-7 evidence: count/fill were stalled on
// 2.4M atomics hitting 25k cache lines (96/line). Replicate counters 8x by
// blockIdx&7; count and fill use IDENTICAL grids so each face hits the same
// replica in both phases -> exact sub-range allocation, 1/8 contention.
// ---------------------------------------------------------------------------

// Phase 1: per-face degree count into replica (blockIdx&7).
__global__ __launch_bounds__(256) void ul_count8(
    const int* __restrict__ faces, int* __restrict__ cnt8)
{
    int t = blockIdx.x * blockDim.x + threadIdx.x;
    if (t >= TOTF) return;
    int* cnt = cnt8 + (size_t)(blockIdx.x & (NREP - 1)) * TOTV;
    int off = (t / FFC) * NVV;
    const int* fp = faces + (size_t)t * 3;
    atomicAdd(&cnt[fp[0] + off], 2);
    atomicAdd(&cnt[fp[1] + off], 2);
    atomicAdd(&cnt[fp[2] + off], 2);
}

// Phase 2a: sum the 8 replicas, write degs, block-exclusive scan of sums.
__global__ __launch_bounds__(256) void ul_scan1(
    const int* __restrict__ cnt8, int* __restrict__ rowptr,
    int* __restrict__ degs, int* __restrict__ bsum)
{
    __shared__ int s[256];
    int blk = blockIdx.x, t = threadIdx.x;
    int base = blk * 1024 + t * 4;
    int4 x = make_int4(0, 0, 0, 0);
    if (base + 3 < TOTV) {
        for (int r = 0; r < NREP; ++r) {
            int4 c = *(const int4*)(cnt8 + (size_t)r * TOTV + base);
            x.x += c.x; x.y += c.y; x.z += c.z; x.w += c.w;
        }
    } else if (base < TOTV) {
        for (int r = 0; r < NREP; ++r) {
            const int* c = cnt8 + (size_t)r * TOTV;
            x.x += c[base];
            if (base + 1 < TOTV) x.y += c[base + 1];
            if (base + 2 < TOTV) x.z += c[base + 2];
        }
    }
    // degrees (sum over replicas)
    if (base + 3 < TOTV) *(int4*)(degs + base) = x;
    else if (base < TOTV) {
        degs[base] = x.x;
        if (base + 1 < TOTV) degs[base + 1] = x.y;
        if (base + 2 < TOTV) degs[base + 2] = x.z;
    }
    int ts = x.x + x.y + x.z + x.w;
    s[t] = ts;
    __syncthreads();
    for (int o = 1; o < 256; o <<= 1) {
        int v = (t >= o) ? s[t - o] : 0;
        __syncthreads();
        s[t] += v;
        __syncthreads();
    }
    int ex = s[t] - ts;                   // exclusive offset within block
    int4 r;
    r.x = ex;
    r.y = ex + x.x;
    r.z = ex + x.x + x.y;
    r.w = ex + x.x + x.y + x.z;
    if (base + 3 < TOTV) *(int4*)(rowptr + base) = r;
    else if (base < TOTV) {
        rowptr[base] = r.x;
        if (base + 1 < TOTV) rowptr[base + 1] = r.y;
        if (base + 2 < TOTV) rowptr[base + 2] = r.z;
    }
    if (t == 255) bsum[blk] = s[255];
}

// Phase 2b: scan the 391 block sums (single block of 512).
__global__ __launch_bounds__(512) void ul_scan2(
    const int* __restrict__ bsum, int* __restrict__ boff)
{
    __shared__ int s[512];
    int t = threadIdx.x;
    int v = (t < NB_SCAN) ? bsum[t] : 0;
    s[t] = v;
    __syncthreads();
    for (int o = 1; o < 512; o <<= 1) {
        int w = (t >= o) ? s[t - o] : 0;
        __syncthreads();
        s[t] += w;
        __syncthreads();
    }
    if (t < NB_SCAN) boff[t] = s[t] - v;  // exclusive
}

// Phase 2c: finalize rowptr (global exclusive starts) AND convert cnt8 in
// place into per-replica cursors: cur_r[v] = rowptr[v] + sum_{s<r} cnt_s[v].
__global__ __launch_bounds__(256) void ul_scan3x(
    int* __restrict__ rowptr, const int* __restrict__ boff, int* __restrict__ cnt8)
{
    int blk = blockIdx.x, t = threadIdx.x;
    int base = blk * 1024 + t * 4;
    if (base >= TOTV) return;
    int o = boff[blk];
    if (base + 3 < TOTV) {
        int4 r = *(const int4*)(rowptr + base);
        r.x += o; r.y += o; r.z += o; r.w += o;
        *(int4*)(rowptr + base) = r;
        int run0 = r.x, run1 = r.y, run2 = r.z, run3 = r.w;
        for (int rep = 0; rep < NREP; ++rep) {
            int4* p = (int4*)(cnt8 + (size_t)rep * TOTV + base);
            int4 c = *p;
            *p = make_int4(run0, run1, run2, run3);
            run0 += c.x; run1 += c.y; run2 += c.z; run3 += c.w;
        }
    } else {
        for (int k = 0; k < 4 && base + k < TOTV; ++k) {
            int v = rowptr[base + k] + o;
            rowptr[base + k] = v;
            int run = v;
            for (int rep = 0; rep < NREP; ++rep) {
                size_t idx = (size_t)rep * TOTV + base + k;
                int c = cnt8[idx];
                cnt8[idx] = run;
                run += c;
            }
        }
    }
}

// Phase 3: fill adjacency via replica cursors. Same grid/replica mapping as
// ul_count8, so each replica's sub-range receives exactly its counted items.
// All cursor values are even -> int2 stores 8B-aligned.
__global__ __launch_bounds__(256) void ul_fill8(
    const int* __restrict__ faces, int* __restrict__ cur, int* __restrict__ adj)
{
    int t = blockIdx.x * blockDim.x + threadIdx.x;
    if (t >= TOTF) return;
    int* c = cur + (size_t)(blockIdx.x & (NREP - 1)) * TOTV;
    int off = (t / FFC) * NVV;
    const int* fp = faces + (size_t)t * 3;
    int ia = fp[0] + off, ib = fp[1] + off, ic = fp[2] + off;
    int pa = atomicAdd(&c[ia], 2); *(int2*)(adj + pa) = make_int2(ib, ic);
    int pb = atomicAdd(&c[ib], 2); *(int2*)(adj + pb) = make_int2(ia, ic);
    int pc = atomicAdd(&c[ic], 2); *(int2*)(adj + pc) = make_int2(ia, ib);
}

// Phase 4: gather + finalize. One wave per vertex, lane = dim.
// 8+4+tail unroll keeps up to 8 neighbor-row loads in flight per wave.
__global__ __launch_bounds__(256) void ul_gather(
    const float* __restrict__ v, const int* __restrict__ rowptr,
    const int* __restrict__ degs, const int* __restrict__ adj,
    float* __restrict__ out)
{
    int gid  = blockIdx.x * blockDim.x + threadIdx.x;
    int wid  = gid >> 6;
    int lane = gid & 63;
    if (wid >= TOTV) return;

    int start = rowptr[wid];
    int dgi   = degs[wid];
    int end   = start + dgi;
    float vi  = v[(size_t)wid * DD + lane];   // independent load, adds MLP

    float acc = 0.0f;
    for (int base = start; base < end; base += 64) {
        int n  = min(64, end - base);
        int jv = (base + lane < end) ? adj[base + lane] : 0;
        int m = 0;
        for (; m + 8 <= n; m += 8) {
            int j0 = __shfl(jv, m);
            int j1 = __shfl(jv, m + 1);
            int j2 = __shfl(jv, m + 2);
            int j3 = __shfl(jv, m + 3);
            int j4 = __shfl(jv, m + 4);
            int j5 = __shfl(jv, m + 5);
            int j6 = __shfl(jv, m + 6);
            int j7 = __shfl(jv, m + 7);
            float a0 = v[(size_t)j0 * DD + lane];
            float a1 = v[(size_t)j1 * DD + lane];
            float a2 = v[(size_t)j2 * DD + lane];
            float a3 = v[(size_t)j3 * DD + lane];
            float a4 = v[(size_t)j4 * DD + lane];
            float a5 = v[(size_t)j5 * DD + lane];
            float a6 = v[(size_t)j6 * DD + lane];
            float a7 = v[(size_t)j7 * DD + lane];
            acc += ((a0 + a1) + (a2 + a3)) + ((a4 + a5) + (a6 + a7));
        }
        if (m + 4 <= n) {
            int j0 = __shfl(jv, m);
            int j1 = __shfl(jv, m + 1);
            int j2 = __shfl(jv, m + 2);
            int j3 = __shfl(jv, m + 3);
            float a0 = v[(size_t)j0 * DD + lane];
            float a1 = v[(size_t)j1 * DD + lane];
            float a2 = v[(size_t)j2 * DD + lane];
            float a3 = v[(size_t)j3 * DD + lane];
            acc += (a0 + a1) + (a2 + a3);
            m += 4;
        }
        for (; m < n; ++m) {
            int j = __shfl(jv, m);
            acc += v[(size_t)j * DD + lane];
        }
    }
    float dg = (float)dgi;
    out[(size_t)wid * DD + lane] = (dg * vi - acc) / (dg + 1e-12f);
}

// ---------------------------------------------------------------------------
// Fallback path (round-2 atomic scatter) in case ws_size is tiny.
// ---------------------------------------------------------------------------
__global__ __launch_bounds__(256) void ul_scatter(
    const float* __restrict__ v, const int* __restrict__ faces,
    float* __restrict__ nbr, float* __restrict__ deg)
{
    int gid  = blockIdx.x * blockDim.x + threadIdx.x;
    int wid  = gid >> 6;
    int lane = gid & 63;
    if (wid >= TOTF) return;
    int off = (wid / FFC) * NVV;
    const int* fp = faces + (size_t)wid * 3;
    int ia = fp[0] + off, ib = fp[1] + off, ic = fp[2] + off;
    float va = v[(size_t)ia * DD + lane];
    float vb = v[(size_t)ib * DD + lane];
    float vc = v[(size_t)ic * DD + lane];
    atomicAdd(&nbr[(size_t)ia * DD + lane], vb + vc);
    atomicAdd(&nbr[(size_t)ib * DD + lane], va + vc);
    atomicAdd(&nbr[(size_t)ic * DD + lane], va + vb);
    if (lane < 3) {
        int t = (lane == 0) ? ia : ((lane == 1) ? ib : ic);
        atomicAdd(&deg[t], 2.0f);
    }
}

__global__ __launch_bounds__(256) void ul_finalize(
    const float4* __restrict__ v4, const float* __restrict__ deg,
    float4* __restrict__ out4, int n4)
{
    int i = blockIdx.x * blockDim.x + threadIdx.x;
    if (i >= n4) return;
    float d = deg[i >> 4];
    float4 vv = v4[i];
    float4 nb = out4[i];
    float inv = 1.0f / (d + 1e-12f);
    float4 r;
    r.x = (d * vv.x - nb.x) * inv;
    r.y = (d * vv.y - nb.y) * inv;
    r.z = (d * vv.z - nb.z) * inv;
    r.w = (d * vv.w - nb.w) * inv;
    out4[i] = r;
}

// ---------------------------------------------------------------------------

extern "C" void kernel_launch(void* const* d_in, const int* in_sizes, int n_in,
                              void* d_out, int out_size, void* d_ws, size_t ws_size,
                              hipStream_t stream)
{
    const float* verts = (const float*)d_in[0];
    const int*   faces = (const int*)d_in[1];
    float*       out   = (float*)d_out;

    // Workspace layout (ints), 256B-aligned sections:
    //   cnt8  [NREP*TOTV]  (counts, then rewritten in place as cursors)
    //   rowptr[TOTV]       (global exclusive starts)
    //   degs  [TOTV]
    //   bsum  [512]
    //   boff  [512]
    //   adj   [TOTE]
    size_t o_cnt8   = 0;
    size_t o_rowptr = o_cnt8   + ((size_t)NREP * TOTV * 4 + 255) / 256 * 256;
    size_t o_degs   = o_rowptr + ((size_t)TOTV * 4 + 255) / 256 * 256;
    size_t o_bsum   = o_degs   + ((size_t)TOTV * 4 + 255) / 256 * 256;
    size_t o_boff   = o_bsum   + 512 * 4;
    size_t o_adj    = o_boff   + 512 * 4;
    size_t needed   = o_adj + (size_t)TOTE * 4;

    if (ws_size >= needed) {
        int* cnt8   = (int*)((char*)d_ws + o_cnt8);
        int* rowptr = (int*)((char*)d_ws + o_rowptr);
        int* degs   = (int*)((char*)d_ws + o_degs);
        int* bsum   = (int*)((char*)d_ws + o_bsum);
        int* boff   = (int*)((char*)d_ws + o_boff);
        int* adj    = (int*)((char*)d_ws + o_adj);

        hipMemsetAsync(cnt8, 0, (size_t)NREP * TOTV * 4, stream);

        int fillBlocks = (TOTF + 255) / 256;
        ul_count8<<<fillBlocks, 256, 0, stream>>>(faces, cnt8);
        ul_scan1 <<<NB_SCAN, 256, 0, stream>>>(cnt8, rowptr, degs, bsum);
        ul_scan2 <<<1, 512, 0, stream>>>(bsum, boff);
        ul_scan3x<<<NB_SCAN, 256, 0, stream>>>(rowptr, boff, cnt8);
        ul_fill8 <<<fillBlocks, 256, 0, stream>>>(faces, cnt8, adj);

        long long thr = (long long)TOTV * 64;
        ul_gather<<<(int)((thr + 255) / 256), 256, 0, stream>>>(
            verts, rowptr, degs, adj, out);
    } else {
        // Fallback: float-atomic scatter (round-2 path).
        float* deg = (float*)d_ws;
        hipMemsetAsync(d_out, 0, (size_t)out_size * sizeof(float), stream);
        hipMemsetAsync(deg,   0, (size_t)TOTV * sizeof(float), stream);
        long long thr = (long long)TOTF * 64;
        ul_scatter<<<(int)((thr + 255) / 256), 256, 0, stream>>>(verts, faces, out, deg);
        int n4 = out_size / 4;
        ul_finalize<<<(n4 + 255) / 256, 256, 0, stream>>>(
            (const float4*)verts, deg, (float4*)out, n4);
    }
}

// Round 10
// 501.617 us; speedup vs baseline: 1.2576x; 1.2576x over previous
//
#include <hip/hip_runtime.h>

// Problem constants (fixed by the reference):
//   B=4, NV=100000, F=200000, D=64
#define BB    4
#define NVV   100000
#define FFC   200000
#define DD    64
#define TOTV  400000              // B*NV
#define TOTF  800000              // B*F
#define TOTE  4800000             // 6 directed edges per face
#define NPART 64                  // dst-partitions (vertex ranges)
#define VPP   6250                // TOTV / NPART exactly
#define FPW   1536                // faces per WG in bucket phase
#define NWGA  ((TOTF + FPW - 1) / FPW)   // 521 WGs
#define ROUNDS (FPW / 256)        // 6 rounds of 256 faces
#define BTHREADS 1024
#define CHUNK 7                   // ceil(VPP / BTHREADS)

__device__ __forceinline__ int part_of(int v) { return v / VPP; }

// ---------------------------------------------------------------------------
// Round-8 evidence: scattered per-lane global atomics/stores cap at ~11.7G
// transactions/s (=750GB/s of 64B lines), independent of address spread.
// This build does all per-edge scatter work in LDS; global traffic is
// coalesced runs. Buckets live in d_out (dead before gather).
// ---------------------------------------------------------------------------

// Pre-pass: edges per dst-partition. LDS histogram, 64 global atomics/WG.
__global__ __launch_bounds__(256) void ul_pcount(
    const int* __restrict__ faces, int* __restrict__ partCnt)
{
    __shared__ int h[NPART];
    int tid = threadIdx.x;
    if (tid < NPART) h[tid] = 0;
    __syncthreads();
    for (int t = blockIdx.x * blockDim.x + tid; t < TOTF; t += gridDim.x * blockDim.x) {
        int off = (t / FFC) * NVV;
        const int* fp = faces + (size_t)t * 3;
        int a = fp[0] + off, b = fp[1] + off, c = fp[2] + off;
        atomicAdd(&h[part_of(a)], 2);
        atomicAdd(&h[part_of(b)], 2);
        atomicAdd(&h[part_of(c)], 2);
    }
    __syncthreads();
    if (tid < NPART && h[tid]) atomicAdd(&partCnt[tid], h[tid]);
}

// Scan the 64 partition counts -> pbase (exclusive starts) + pcur (cursors).
__global__ void ul_pscan(const int* __restrict__ partCnt,
                         int* __restrict__ pbase, int* __restrict__ pcur)
{
    __shared__ int s[NPART];
    int t = threadIdx.x;              // 64 threads
    int v = partCnt[t];
    s[t] = v;
    __syncthreads();
    for (int o = 1; o < NPART; o <<= 1) {
        int w = (t >= o) ? s[t - o] : 0;
        __syncthreads();
        s[t] += w;
        __syncthreads();
    }
    int ex = s[t] - v;
    pbase[t] = ex;
    pcur[t]  = ex;
}

// Bucket phase: 256 faces/round -> 1536 edges -> LDS hist/scan/reorder ->
// coalesced partition-grouped flush to global buckets. 64 cursor atomics/round.
__global__ __launch_bounds__(256) void ul_bucket(
    const int* __restrict__ faces, int* __restrict__ pcur, int2* __restrict__ bucket)
{
    __shared__ int   hist[NPART];
    __shared__ int   offs[NPART];
    __shared__ int   gbase[NPART];
    __shared__ int2  ebuf[1536];
    __shared__ short pidb[1536];
    int tid = threadIdx.x;
    int wg  = blockIdx.x;

    for (int r = 0; r < ROUNDS; ++r) {
        int f = wg * FPW + r * 256 + tid;
        bool valid = f < TOTF;
        int dsts[6], srcs[6], slot[6];
        if (valid) {
            int off = (f / FFC) * NVV;
            const int* fp = faces + (size_t)f * 3;
            int a = fp[0] + off, b = fp[1] + off, c = fp[2] + off;
            dsts[0] = a; srcs[0] = b;  dsts[1] = a; srcs[1] = c;
            dsts[2] = b; srcs[2] = a;  dsts[3] = b; srcs[3] = c;
            dsts[4] = c; srcs[4] = a;  dsts[5] = c; srcs[5] = b;
        }
        if (tid < NPART) hist[tid] = 0;
        __syncthreads();
        if (valid) {
            #pragma unroll
            for (int k = 0; k < 6; ++k)
                slot[k] = atomicAdd(&hist[part_of(dsts[k])], 1);
        }
        __syncthreads();
        if (tid < NPART) offs[tid] = hist[tid];
        __syncthreads();
        for (int o = 1; o < NPART; o <<= 1) {
            int w = 0;
            if (tid < NPART && tid >= o) w = offs[tid - o];
            __syncthreads();
            if (tid < NPART) offs[tid] += w;
            __syncthreads();
        }
        // offs inclusive -> exclusive; reserve global cursor space per partition.
        if (tid < NPART) {
            offs[tid] -= hist[tid];
            gbase[tid] = atomicAdd(&pcur[tid], hist[tid]);
        }
        __syncthreads();
        int roundEdges = offs[NPART - 1] + hist[NPART - 1];
        if (valid) {
            #pragma unroll
            for (int k = 0; k < 6; ++k) {
                int p   = part_of(dsts[k]);
                int pos = offs[p] + slot[k];
                ebuf[pos] = make_int2(dsts[k], srcs[k]);
                pidb[pos] = (short)p;
            }
        }
        __syncthreads();
        // coalesced flush: consecutive e within a partition group -> consecutive
        // global addresses (runs of ~24 int2 = 192B).
        for (int e = tid; e < roundEdges; e += 256) {
            int q = pidb[e];
            bucket[gbase[q] + (e - offs[q])] = ebuf[e];
        }
        __syncthreads();   // protect hist/offs/ebuf reuse next round
    }
}

// Build phase: one WG per partition. LDS histogram + scan over 6250 vertices,
// coalesced rowptr/degs writes, then LDS-cursor scatter of src ids into the
// partition's 300KB adj window (L2-absorbed, single XCD).
__global__ __launch_bounds__(BTHREADS) void ul_build(
    const int2* __restrict__ bucket, const int* __restrict__ pbase,
    const int* __restrict__ partCnt,
    int* __restrict__ adj, int* __restrict__ rowptr, int* __restrict__ degs)
{
    __shared__ int lcnt[VPP];
    __shared__ int lofs[VPP];
    __shared__ int psum[BTHREADS];
    int p     = blockIdx.x;
    int tid   = threadIdx.x;
    int vbase = p * VPP;
    int ebase = pbase[p];
    int ecnt  = partCnt[p];

    for (int i = tid; i < VPP; i += BTHREADS) lcnt[i] = 0;
    __syncthreads();
    for (int e = tid; e < ecnt; e += BTHREADS)
        atomicAdd(&lcnt[bucket[ebase + e].x - vbase], 1);
    __syncthreads();

    // exclusive scan of lcnt -> lofs (chunked serial + block scan of totals)
    int base_i = tid * CHUNK;
    int run = 0;
    #pragma unroll
    for (int k = 0; k < CHUNK; ++k) {
        int i = base_i + k;
        if (i < VPP) { int c = lcnt[i]; lofs[i] = run; run += c; }
    }
    psum[tid] = run;
    __syncthreads();
    for (int o = 1; o < BTHREADS; o <<= 1) {
        int w = (tid >= o) ? psum[tid - o] : 0;
        __syncthreads();
        psum[tid] += w;
        __syncthreads();
    }
    int excl = psum[tid] - run;
    #pragma unroll
    for (int k = 0; k < CHUNK; ++k) {
        int i = base_i + k;
        if (i < VPP) lofs[i] += excl;
    }
    __syncthreads();

    for (int i = tid; i < VPP; i += BTHREADS) {
        rowptr[vbase + i] = ebase + lofs[i];
        degs  [vbase + i] = lcnt[i];
    }
    __syncthreads();

    // scatter src ids; lofs doubles as cursor (rowptr already persisted)
    for (int e = tid; e < ecnt; e += BTHREADS) {
        int2 ed = bucket[ebase + e];
        int pos = atomicAdd(&lofs[ed.x - vbase], 1);
        adj[ebase + pos] = ed.y;
    }
}

// Gather + finalize. One wave per vertex, lane = dim. 8+4+tail unroll keeps
// up to 8 neighbor-row loads in flight per wave (round-7: top kernel no more).
__global__ __launch_bounds__(256) void ul_gather(
    const float* __restrict__ v, const int* __restrict__ rowptr,
    const int* __restrict__ degs, const int* __restrict__ adj,
    float* __restrict__ out)
{
    int gid  = blockIdx.x * blockDim.x + threadIdx.x;
    int wid  = gid >> 6;
    int lane = gid & 63;
    if (wid >= TOTV) return;

    int start = rowptr[wid];
    int dgi   = degs[wid];
    int end   = start + dgi;
    float vi  = v[(size_t)wid * DD + lane];

    float acc = 0.0f;
    for (int base = start; base < end; base += 64) {
        int n  = min(64, end - base);
        int jv = (base + lane < end) ? adj[base + lane] : 0;
        int m = 0;
        for (; m + 8 <= n; m += 8) {
            int j0 = __shfl(jv, m);
            int j1 = __shfl(jv, m + 1);
            int j2 = __shfl(jv, m + 2);
            int j3 = __shfl(jv, m + 3);
            int j4 = __shfl(jv, m + 4);
            int j5 = __shfl(jv, m + 5);
            int j6 = __shfl(jv, m + 6);
            int j7 = __shfl(jv, m + 7);
            float a0 = v[(size_t)j0 * DD + lane];
            float a1 = v[(size_t)j1 * DD + lane];
            float a2 = v[(size_t)j2 * DD + lane];
            float a3 = v[(size_t)j3 * DD + lane];
            float a4 = v[(size_t)j4 * DD + lane];
            float a5 = v[(size_t)j5 * DD + lane];
            float a6 = v[(size_t)j6 * DD + lane];
            float a7 = v[(size_t)j7 * DD + lane];
            acc += ((a0 + a1) + (a2 + a3)) + ((a4 + a5) + (a6 + a7));
        }
        if (m + 4 <= n) {
            int j0 = __shfl(jv, m);
            int j1 = __shfl(jv, m + 1);
            int j2 = __shfl(jv, m + 2);
            int j3 = __shfl(jv, m + 3);
            float a0 = v[(size_t)j0 * DD + lane];
            float a1 = v[(size_t)j1 * DD + lane];
            float a2 = v[(size_t)j2 * DD + lane];
            float a3 = v[(size_t)j3 * DD + lane];
            acc += (a0 + a1) + (a2 + a3);
            m += 4;
        }
        for (; m < n; ++m) {
            int j = __shfl(jv, m);
            acc += v[(size_t)j * DD + lane];
        }
    }
    float dg = (float)dgi;
    out[(size_t)wid * DD + lane] = (dg * vi - acc) / (dg + 1e-12f);
}

// ---------------------------------------------------------------------------
// Fallback path (round-2 atomic scatter) in case ws_size is tiny.
// ---------------------------------------------------------------------------
__global__ __launch_bounds__(256) void ul_scatter(
    const float* __restrict__ v, const int* __restrict__ faces,
    float* __restrict__ nbr, float* __restrict__ deg)
{
    int gid  = blockIdx.x * blockDim.x + threadIdx.x;
    int wid  = gid >> 6;
    int lane = gid & 63;
    if (wid >= TOTF) return;
    int off = (wid / FFC) * NVV;
    const int* fp = faces + (size_t)wid * 3;
    int ia = fp[0] + off, ib = fp[1] + off, ic = fp[2] + off;
    float va = v[(size_t)ia * DD + lane];
    float vb = v[(size_t)ib * DD + lane];
    float vc = v[(size_t)ic * DD + lane];
    atomicAdd(&nbr[(size_t)ia * DD + lane], vb + vc);
    atomicAdd(&nbr[(size_t)ib * DD + lane], va + vc);
    atomicAdd(&nbr[(size_t)ic * DD + lane], va + vb);
    if (lane < 3) {
        int t = (lane == 0) ? ia : ((lane == 1) ? ib : ic);
        atomicAdd(&deg[t], 2.0f);
    }
}

__global__ __launch_bounds__(256) void ul_finalize(
    const float4* __restrict__ v4, const float* __restrict__ deg,
    float4* __restrict__ out4, int n4)
{
    int i = blockIdx.x * blockDim.x + threadIdx.x;
    if (i >= n4) return;
    float d = deg[i >> 4];
    float4 vv = v4[i];
    float4 nb = out4[i];
    float inv = 1.0f / (d + 1e-12f);
    float4 r;
    r.x = (d * vv.x - nb.x) * inv;
    r.y = (d * vv.y - nb.y) * inv;
    r.z = (d * vv.z - nb.z) * inv;
    r.w = (d * vv.w - nb.w) * inv;
    out4[i] = r;
}

// ---------------------------------------------------------------------------

extern "C" void kernel_launch(void* const* d_in, const int* in_sizes, int n_in,
                              void* d_out, int out_size, void* d_ws, size_t ws_size,
                              hipStream_t stream)
{
    const float* verts = (const float*)d_in[0];
    const int*   faces = (const int*)d_in[1];
    float*       out   = (float*)d_out;

    // Workspace layout (256B-aligned sections):
    //   rowptr [TOTV]   degs [TOTV]   partCnt[64]  pbase[64]  pcur[64]
    //   adj    [TOTE]
    // The 38.4MB edge bucket lives in d_out (102MB) — dead before gather.
    size_t o_rowptr = 0;
    size_t o_degs   = o_rowptr + ((size_t)TOTV * 4 + 255) / 256 * 256;
    size_t o_pcnt   = o_degs   + ((size_t)TOTV * 4 + 255) / 256 * 256;
    size_t o_pbase  = o_pcnt   + 256;
    size_t o_pcur   = o_pbase  + 256;
    size_t o_adj    = o_pcur   + 256;
    size_t needed   = o_adj + (size_t)TOTE * 4;

    if (ws_size >= needed) {
        int* rowptr  = (int*)((char*)d_ws + o_rowptr);
        int* degs    = (int*)((char*)d_ws + o_degs);
        int* partCnt = (int*)((char*)d_ws + o_pcnt);
        int* pbase   = (int*)((char*)d_ws + o_pbase);
        int* pcur    = (int*)((char*)d_ws + o_pcur);
        int* adj     = (int*)((char*)d_ws + o_adj);
        int2* bucket = (int2*)d_out;

        hipMemsetAsync(partCnt, 0, NPART * 4, stream);

        ul_pcount<<<512, 256, 0, stream>>>(faces, partCnt);
        ul_pscan <<<1, NPART, 0, stream>>>(partCnt, pbase, pcur);
        ul_bucket<<<NWGA, 256, 0, stream>>>(faces, pcur, bucket);
        ul_build <<<NPART, BTHREADS, 0, stream>>>(bucket, pbase, partCnt,
                                                  adj, rowptr, degs);

        long long thr = (long long)TOTV * 64;
        ul_gather<<<(int)((thr + 255) / 256), 256, 0, stream>>>(
            verts, rowptr, degs, adj, out);
    } else {
        // Fallback: float-atomic scatter (round-2 path).
        float* deg = (float*)d_ws;
        hipMemsetAsync(d_out, 0, (size_t)out_size * sizeof(float), stream);
        hipMemsetAsync(deg,   0, (size_t)TOTV * sizeof(float), stream);
        long long thr = (long long)TOTF * 64;
        ul_scatter<<<(int)((thr + 255) / 256), 256, 0, stream>>>(verts, faces, out, deg);
        int n4 = out_size / 4;
        ul_finalize<<<(n4 + 255) / 256, 256, 0, stream>>>(
            (const float4*)verts, deg, (float4*)out, n4);
    }
}